// Round 2
// baseline (3201.326 us; speedup 1.0000x reference)
//
#include <hip/hip_runtime.h>
#include <hip/hip_bf16.h>
#include <stdint.h>

// VanillaTransformer: V=32000 S=2048 D=768 H=12 HD=64 L=6, batch=2 -> 4096 tokens
// Inputs: f32 (+ idx int32). Output: f32 logits [2,2048,32000].
// Internals: residual stream f32 in ws; GEMMs bf16 MFMA w/ f32 accumulate;
// weights converted f32->bf16 on the fly during LDS staging.

typedef unsigned short u16;
typedef __attribute__((ext_vector_type(8))) __bf16 bf16x8;
typedef __attribute__((ext_vector_type(4))) float f32x4;
typedef __attribute__((ext_vector_type(4))) unsigned int u32x4;
typedef __attribute__((ext_vector_type(4))) unsigned short u16x4;

#define MFMA16(a, b, c) __builtin_amdgcn_mfma_f32_16x16x32_bf16((a), (b), (c), 0, 0, 0)

__device__ __forceinline__ float b2f(u16 u) {
  union { unsigned int i; float f; } x; x.i = ((unsigned int)u) << 16; return x.f;
}
__device__ __forceinline__ u16 f2b(float f) {  // round-to-nearest-even
  union { float f; unsigned int i; } x; x.f = f;
  unsigned int r = x.i + 0x7fffu + ((x.i >> 16) & 1u);
  return (u16)(r >> 16);
}
__device__ __forceinline__ float gelu_f(float v) {  // tanh-approx (jax default)
  const float t = 0.7978845608028654f * (v + 0.044715f * v * v * v);
  const float e = __expf(-2.f * fabsf(t));
  float th = (1.f - e) / (1.f + e);
  th = (t < 0.f) ? -th : th;
  return 0.5f * v * (1.f + th);
}

// ---------------- embedding: x[t,:] = tok_emb[idx[t]] + pos_enc[t%2048] ------
__global__ __launch_bounds__(256) void embed_kernel(
    const int* __restrict__ idx, const float* __restrict__ tok,
    const float* __restrict__ pos, float* __restrict__ x) {
  const int t = blockIdx.x;
  const int s = t & 2047;
  const int tid = threadIdx.x;
  const size_t to = (size_t)idx[t] * 768;
  const size_t po = (size_t)s * 768;
  float* xr = x + (size_t)t * 768;
#pragma unroll
  for (int i = 0; i < 3; ++i) {
    const int d = tid + i * 256;
    xr[d] = tok[to + d] + pos[po + d];
  }
}

// ---------------- LayerNorm: f32 in -> bf16 out ------------------------------
__global__ __launch_bounds__(256) void ln_kernel(
    const float* __restrict__ x, const float* __restrict__ g,
    const float* __restrict__ b, u16* __restrict__ out) {
  __shared__ float red[8];
  const int row = blockIdx.x;
  const int tid = threadIdx.x;
  const float* xr = x + (size_t)row * 768;
  const float v0 = xr[tid], v1 = xr[tid + 256], v2 = xr[tid + 512];
  float s = v0 + v1 + v2;
#pragma unroll
  for (int m = 1; m < 64; m <<= 1) s += __shfl_xor(s, m);
  const int w = tid >> 6, lane = tid & 63;
  if (lane == 0) red[w] = s;
  __syncthreads();
  const float mu = (red[0] + red[1] + red[2] + red[3]) * (1.f / 768.f);
  const float d0 = v0 - mu, d1 = v1 - mu, d2 = v2 - mu;
  float q = d0 * d0 + d1 * d1 + d2 * d2;
#pragma unroll
  for (int m = 1; m < 64; m <<= 1) q += __shfl_xor(q, m);
  if (lane == 0) red[4 + w] = q;
  __syncthreads();
  const float var = (red[4] + red[5] + red[6] + red[7]) * (1.f / 768.f);
  const float rs = rsqrtf(var + 1e-5f);
  u16* orow = out + (size_t)row * 768;
  orow[tid]       = f2b(d0 * rs * g[tid]       + b[tid]);
  orow[tid + 256] = f2b(d1 * rs * g[tid + 256] + b[tid + 256]);
  orow[tid + 512] = f2b(d2 * rs * g[tid + 512] + b[tid + 512]);
}

// ---------------- GEMM: C[M,N] = A[M,K](bf16) * B[N,K](f32)^T ----------------
// MODE 0: outb = bf16(acc + bias)
// MODE 1: outb = bf16(gelu(acc + bias))
// MODE 2: resid += acc + bias (f32); optional bf16 mirror of new resid
// MODE 3: outf = acc + bias (f32)
// grid = (N/128, M/128), block = 256 (4 waves), tile 128x128, BK=64.
template <int MODE>
__global__ __launch_bounds__(256) void gemm_bt(
    const u16* __restrict__ A, const float* __restrict__ B,
    const float* __restrict__ bias, u16* __restrict__ outb,
    float* __restrict__ outf, float* __restrict__ resid,
    u16* __restrict__ mirror, int N, int K) {
  __shared__ alignas(16) u16 As[128 * 64];
  __shared__ alignas(16) u16 Bs[128 * 64];
  const int tid = threadIdx.x;
  const int lane = tid & 63;
  const int w = tid >> 6;
  const int wr = (w >> 1) * 64;  // wave row offset in tile
  const int wc = (w & 1) * 64;   // wave col offset in tile
  const int fr = lane & 15;
  const int fg = lane >> 4;
  const int bn0 = blockIdx.x * 128;
  const int bm0 = blockIdx.y * 128;

  f32x4 acc[4][4] = {};

  for (int bk0 = 0; bk0 < K; bk0 += 64) {
    __syncthreads();
    // A: bf16, 1024 chunks of 16B
#pragma unroll
    for (int i = 0; i < 4; ++i) {
      const int c = i * 256 + tid;
      const int row = c >> 3;
      const int e0 = (c & 7) * 8;
      *(u32x4*)&As[row * 64 + e0] =
          *(const u32x4*)&A[(size_t)(bm0 + row) * K + bk0 + e0];
    }
    // B: f32 -> bf16, 2048 chunks of 4 floats (16B read, 8B LDS write)
#pragma unroll
    for (int i = 0; i < 8; ++i) {
      const int c = i * 256 + tid;
      const int row = c >> 4;
      const int e0 = (c & 15) * 4;
      const f32x4 fv = *(const f32x4*)&B[(size_t)(bn0 + row) * K + bk0 + e0];
      u16x4 pv;
#pragma unroll
      for (int j = 0; j < 4; ++j) pv[j] = f2b(fv[j]);
      *(u16x4*)&Bs[row * 64 + e0] = pv;
    }
    __syncthreads();
#pragma unroll
    for (int kk = 0; kk < 64; kk += 32) {
      bf16x8 af[4], bfv[4];
#pragma unroll
      for (int m = 0; m < 4; ++m)
        af[m] = *(const bf16x8*)&As[(wr + m * 16 + fr) * 64 + kk + fg * 8];
#pragma unroll
      for (int n = 0; n < 4; ++n)
        bfv[n] = *(const bf16x8*)&Bs[(wc + n * 16 + fr) * 64 + kk + fg * 8];
#pragma unroll
      for (int m = 0; m < 4; ++m)
#pragma unroll
        for (int n = 0; n < 4; ++n)
          acc[m][n] = MFMA16(af[m], bfv[n], acc[m][n]);
    }
  }

#pragma unroll
  for (int n = 0; n < 4; ++n) {
    const int col = bn0 + wc + n * 16 + fr;
    const float bv = bias ? bias[col] : 0.0f;
#pragma unroll
    for (int m = 0; m < 4; ++m) {
#pragma unroll
      for (int r = 0; r < 4; ++r) {
        const int row = bm0 + wr + m * 16 + fg * 4 + r;
        float v = acc[m][n][r] + bv;
        if (MODE == 1) v = gelu_f(v);
        const size_t off = (size_t)row * N + col;
        if (MODE == 2) {
          const float nv = resid[off] + v;
          resid[off] = nv;
          if (mirror) mirror[off] = f2b(nv);
        } else if (MODE == 3) {
          outf[off] = v;
        } else {
          outb[off] = f2b(v);
        }
      }
    }
  }
}

// ---------------- fused attention (no causal mask) ---------------------------
// grid = (S/64, H, B). block = 256 (4 waves); wave handles 16 q-rows.
// qkv layout: [token][2304] with q|k|v each 768 (12 heads * 64), bf16.
__global__ __launch_bounds__(256) void attn_kernel(
    const u16* __restrict__ qkv, u16* __restrict__ y) {
  __shared__ alignas(16) u16 Ks[32 * 64];     // K tile  [32 keys][64]
  __shared__ alignas(16) u16 VTs[64 * 32];    // V tile^T [64 d][32 keys]
  __shared__ alignas(16) u16 Ps[4][16 * 32];  // per-wave P [16 q][32 keys]
  const int tid = threadIdx.x;
  const int lane = tid & 63;
  const int w = tid >> 6;
  const int fr = lane & 15;
  const int fg = lane >> 4;
  const int qb = blockIdx.x;
  const int hh = blockIdx.y;
  const int bb = blockIdx.z;
  const size_t tb = (size_t)bb * 2048 * 2304;
  const int q0 = qb * 64 + w * 16;

  const bf16x8 qf0 =
      *(const bf16x8*)&qkv[tb + (size_t)(q0 + fr) * 2304 + hh * 64 + fg * 8];
  const bf16x8 qf1 =
      *(const bf16x8*)&qkv[tb + (size_t)(q0 + fr) * 2304 + hh * 64 + 32 + fg * 8];

  f32x4 oacc[4] = {};
  float mrow[4] = {-INFINITY, -INFINITY, -INFINITY, -INFINITY};
  float lrow[4] = {0.f, 0.f, 0.f, 0.f};

  const int skey = tid >> 3;       // staging: key 0..31
  const int se0 = (tid & 7) * 8;   // staging: elem offset

  for (int kt = 0; kt < 2048; kt += 32) {
    __syncthreads();  // previous iteration's LDS reads done
    {
      const size_t rbase = tb + (size_t)(kt + skey) * 2304 + hh * 64 + se0;
      *(u32x4*)&Ks[skey * 64 + se0] = *(const u32x4*)&qkv[rbase + 768];
      union { u32x4 v; u16 s[8]; } tmp;
      tmp.v = *(const u32x4*)&qkv[rbase + 1536];
#pragma unroll
      for (int j = 0; j < 8; ++j) VTs[(se0 + j) * 32 + skey] = tmp.s[j];
    }
    __syncthreads();

    // scores: [16 q][32 keys] over HD=64
    f32x4 s0 = {}, s1 = {};
    {
      const bf16x8 k00 = *(const bf16x8*)&Ks[fr * 64 + fg * 8];
      const bf16x8 k01 = *(const bf16x8*)&Ks[fr * 64 + 32 + fg * 8];
      const bf16x8 k10 = *(const bf16x8*)&Ks[(16 + fr) * 64 + fg * 8];
      const bf16x8 k11 = *(const bf16x8*)&Ks[(16 + fr) * 64 + 32 + fg * 8];
      s0 = MFMA16(qf0, k00, s0);
      s0 = MFMA16(qf1, k01, s0);
      s1 = MFMA16(qf0, k10, s1);
      s1 = MFMA16(qf1, k11, s1);
    }

    float alpha[4];
#pragma unroll
    for (int r = 0; r < 4; ++r) {
      const float a = s0[r] * 0.125f;
      const float c = s1[r] * 0.125f;
      float mx = fmaxf(a, c);
      mx = fmaxf(mx, __shfl_xor(mx, 1));
      mx = fmaxf(mx, __shfl_xor(mx, 2));
      mx = fmaxf(mx, __shfl_xor(mx, 4));
      mx = fmaxf(mx, __shfl_xor(mx, 8));
      const float mn = fmaxf(mrow[r], mx);
      const float al = __expf(mrow[r] - mn);
      const float p0 = __expf(a - mn);
      const float p1 = __expf(c - mn);
      float ps = p0 + p1;
      ps += __shfl_xor(ps, 1);
      ps += __shfl_xor(ps, 2);
      ps += __shfl_xor(ps, 4);
      ps += __shfl_xor(ps, 8);
      lrow[r] = lrow[r] * al + ps;
      mrow[r] = mn;
      alpha[r] = al;
      Ps[w][(fg * 4 + r) * 32 + fr] = f2b(p0);
      Ps[w][(fg * 4 + r) * 32 + 16 + fr] = f2b(p1);
    }
#pragma unroll
    for (int db = 0; db < 4; ++db)
#pragma unroll
      for (int r = 0; r < 4; ++r) oacc[db][r] *= alpha[r];

    // P is wave-private; same-wave DS ordering makes the read-after-write safe.
    const bf16x8 pa = *(const bf16x8*)&Ps[w][fr * 32 + fg * 8];
#pragma unroll
    for (int db = 0; db < 4; ++db) {
      const bf16x8 vb = *(const bf16x8*)&VTs[(db * 16 + fr) * 32 + fg * 8];
      oacc[db] = MFMA16(pa, vb, oacc[db]);
    }
  }

#pragma unroll
  for (int db = 0; db < 4; ++db) {
#pragma unroll
    for (int r = 0; r < 4; ++r) {
      const int row = q0 + fg * 4 + r;
      y[(size_t)(bb * 2048 + row) * 768 + hh * 64 + db * 16 + fr] =
          f2b(oacc[db][r] / lrow[r]);
    }
  }
}

// ---------------- launcher ---------------------------------------------------
extern "C" void kernel_launch(void* const* d_in, const int* in_sizes, int n_in,
                              void* d_out, int out_size, void* d_ws,
                              size_t ws_size, hipStream_t stream) {
  const int*   idx   = (const int*)d_in[0];
  const float* tok   = (const float*)d_in[1];
  const float* pos   = (const float*)d_in[2];
  const float* attnw = (const float*)d_in[3];
  const float* attnb = (const float*)d_in[4];
  const float* projw = (const float*)d_in[5];
  const float* projb = (const float*)d_in[6];
  const float* ln1g  = (const float*)d_in[7];
  const float* ln1b  = (const float*)d_in[8];
  const float* ln2g  = (const float*)d_in[9];
  const float* ln2b  = (const float*)d_in[10];
  const float* fc1w  = (const float*)d_in[11];
  const float* fc1b  = (const float*)d_in[12];
  const float* fc2w  = (const float*)d_in[13];
  const float* fc2b  = (const float*)d_in[14];
  const float* decw  = (const float*)d_in[15];

  char* ws = (char*)d_ws;
  float* x = (float*)(ws);                      // [0, 12.58MB)   4096*768 f32
  u16* h   = (u16*)(ws + 12582912);             // [12.58, 18.87) 4096*768 bf16
  u16* qkv = (u16*)(ws + 18874368);             // [18.87, 37.75) 4096*2304 bf16
  u16* y   = (u16*)(ws + 37748736);             // [37.75, 44.04) 4096*768 bf16
  u16* h2  = (u16*)(ws + 18874368);             // alias qkv+y: 4096*3072 bf16

  embed_kernel<<<4096, 256, 0, stream>>>(idx, tok, pos, x);

  for (int l = 0; l < 6; ++l) {
    ln_kernel<<<4096, 256, 0, stream>>>(x, ln1g + l * 768, ln1b + l * 768, h);
    gemm_bt<0><<<dim3(2304 / 128, 32), 256, 0, stream>>>(
        h, attnw + (size_t)l * 2304 * 768, attnb + l * 2304, qkv, nullptr,
        nullptr, nullptr, 2304, 768);
    attn_kernel<<<dim3(32, 12, 2), 256, 0, stream>>>(qkv, y);
    gemm_bt<2><<<dim3(768 / 128, 32), 256, 0, stream>>>(
        y, projw + (size_t)l * 768 * 768, projb + l * 768, nullptr, nullptr, x,
        nullptr, 768, 768);
    ln_kernel<<<4096, 256, 0, stream>>>(x, ln2g + l * 768, ln2b + l * 768, h);
    gemm_bt<1><<<dim3(3072 / 128, 32), 256, 0, stream>>>(
        h, fc1w + (size_t)l * 3072 * 768, fc1b + l * 3072, h2, nullptr, nullptr,
        nullptr, 3072, 768);
    gemm_bt<2><<<dim3(768 / 128, 32), 256, 0, stream>>>(
        h2, fc2w + (size_t)l * 768 * 3072, fc2b + l * 768, nullptr, nullptr, x,
        (l == 5) ? h : nullptr, 768, 3072);
  }

  gemm_bt<3><<<dim3(32000 / 128, 32), 256, 0, stream>>>(
      h, decw, nullptr, nullptr, (float*)d_out, nullptr, nullptr, 32000, 768);
}

// Round 3
// 2648.664 us; speedup vs baseline: 1.2087x; 1.2087x over previous
//
#include <hip/hip_runtime.h>
#include <hip/hip_bf16.h>
#include <stdint.h>

// VanillaTransformer: V=32000 S=2048 D=768 H=12 HD=64 L=6, batch=2 -> 4096 tokens
// Inputs: f32 (+ idx int32). Output: f32 logits [2,2048,32000].
// Fast path: weights pre-converted f32->bf16 into ws arena once per launch;
// GEMMs use global_load_lds width-16 staging with XOR slot swizzle.

typedef unsigned short u16;
typedef __attribute__((ext_vector_type(8))) __bf16 bf16x8;
typedef __attribute__((ext_vector_type(4))) float f32x4;
typedef __attribute__((ext_vector_type(4))) unsigned int u32x4;
typedef __attribute__((ext_vector_type(4))) unsigned short u16x4;
typedef __attribute__((ext_vector_type(8))) unsigned short u16x8;

#define MFMA16(a, b, c) __builtin_amdgcn_mfma_f32_16x16x32_bf16((a), (b), (c), 0, 0, 0)

__device__ __forceinline__ float b2f(u16 u) {
  union { unsigned int i; float f; } x; x.i = ((unsigned int)u) << 16; return x.f;
}
__device__ __forceinline__ u16 f2b(float f) {  // round-to-nearest-even
  union { float f; unsigned int i; } x; x.f = f;
  unsigned int r = x.i + 0x7fffu + ((x.i >> 16) & 1u);
  return (u16)(r >> 16);
}
__device__ __forceinline__ float gelu_f(float v) {  // tanh-approx (jax default)
  const float t = 0.7978845608028654f * (v + 0.044715f * v * v * v);
  const float e = __expf(-2.f * fabsf(t));
  float th = (1.f - e) / (1.f + e);
  th = (t < 0.f) ? -th : th;
  return 0.5f * v * (1.f + th);
}
// async global->LDS, 16B per lane; l must be wave-uniform (HW adds lane*16).
__device__ __forceinline__ void lds16(u16* l, const u16* g) {
  __builtin_amdgcn_global_load_lds(
      (const __attribute__((address_space(1))) unsigned int*)g,
      (__attribute__((address_space(3))) unsigned int*)l, 16, 0, 0);
}

// ---------------- f32 -> bf16 conversion (weights) ---------------------------
__global__ __launch_bounds__(256) void conv_bf16_kernel(
    const float* __restrict__ src, u16* __restrict__ dst, int n8) {
  int i = blockIdx.x * 256 + threadIdx.x;
  const int stride = gridDim.x * 256;
  for (; i < n8; i += stride) {
    const f32x4 a = *(const f32x4*)&src[(size_t)i * 8];
    const f32x4 b = *(const f32x4*)&src[(size_t)i * 8 + 4];
    u16x8 p;
#pragma unroll
    for (int j = 0; j < 4; ++j) { p[j] = f2b(a[j]); p[4 + j] = f2b(b[j]); }
    *(u16x8*)&dst[(size_t)i * 8] = p;
  }
}

// ---------------- embedding: x[t,:] = tok_emb[idx[t]] + pos_enc[t%2048] ------
__global__ __launch_bounds__(256) void embed_kernel(
    const int* __restrict__ idx, const float* __restrict__ tok,
    const float* __restrict__ pos, float* __restrict__ x) {
  const int t = blockIdx.x;
  const int s = t & 2047;
  const int tid = threadIdx.x;
  const size_t to = (size_t)idx[t] * 768;
  const size_t po = (size_t)s * 768;
  float* xr = x + (size_t)t * 768;
#pragma unroll
  for (int i = 0; i < 3; ++i) {
    const int d = tid + i * 256;
    xr[d] = tok[to + d] + pos[po + d];
  }
}

// ---------------- LayerNorm: f32 in -> bf16 out ------------------------------
__global__ __launch_bounds__(256) void ln_kernel(
    const float* __restrict__ x, const float* __restrict__ g,
    const float* __restrict__ b, u16* __restrict__ out) {
  __shared__ float red[8];
  const int row = blockIdx.x;
  const int tid = threadIdx.x;
  const float* xr = x + (size_t)row * 768;
  const float v0 = xr[tid], v1 = xr[tid + 256], v2 = xr[tid + 512];
  float s = v0 + v1 + v2;
#pragma unroll
  for (int m = 1; m < 64; m <<= 1) s += __shfl_xor(s, m);
  const int w = tid >> 6, lane = tid & 63;
  if (lane == 0) red[w] = s;
  __syncthreads();
  const float mu = (red[0] + red[1] + red[2] + red[3]) * (1.f / 768.f);
  const float d0 = v0 - mu, d1 = v1 - mu, d2 = v2 - mu;
  float q = d0 * d0 + d1 * d1 + d2 * d2;
#pragma unroll
  for (int m = 1; m < 64; m <<= 1) q += __shfl_xor(q, m);
  if (lane == 0) red[4 + w] = q;
  __syncthreads();
  const float var = (red[4] + red[5] + red[6] + red[7]) * (1.f / 768.f);
  const float rs = rsqrtf(var + 1e-5f);
  u16* orow = out + (size_t)row * 768;
  orow[tid]       = f2b(d0 * rs * g[tid]       + b[tid]);
  orow[tid + 256] = f2b(d1 * rs * g[tid + 256] + b[tid + 256]);
  orow[tid + 512] = f2b(d2 * rs * g[tid + 512] + b[tid + 512]);
}

// ===== fast GEMM: C[M,N] = A[M,K](bf16) * B[N,K](bf16)^T, lds-direct staging =
// MODE 0: outb = bf16(acc + bias)
// MODE 1: outb = bf16(gelu(acc + bias))
// MODE 2: resid += acc + bias (f32); optional bf16 mirror of new resid
// MODE 3: outf = acc + bias (f32)
// MFAST=0: grid (N/128, M/128); MFAST=1: grid (M/128, N/128) (B-tile reuse).
template <int MODE, int MFAST>
__global__ __launch_bounds__(256) void gemm_bb(
    const u16* __restrict__ A, const u16* __restrict__ B,
    const float* __restrict__ bias, u16* __restrict__ outb,
    float* __restrict__ outf, float* __restrict__ resid,
    u16* __restrict__ mirror, int N, int K) {
  __shared__ alignas(16) u16 As[128 * 64];
  __shared__ alignas(16) u16 Bs[128 * 64];
  const int tid = threadIdx.x;
  const int lane = tid & 63;
  const int w = tid >> 6;
  const int wr = (w >> 1) * 64;  // wave row offset in tile
  const int wc = (w & 1) * 64;   // wave col offset in tile
  const int fr = lane & 15;
  const int fg = lane >> 4;
  const int bn0 = (MFAST ? blockIdx.y : blockIdx.x) * 128;
  const int bm0 = (MFAST ? blockIdx.x : blockIdx.y) * 128;

  f32x4 acc[4][4] = {};

  // per-call staging: chunk c = i*256 + tid (16B chunks), row = c>>3,
  // swizzled slot = (c&7) ^ (row&7)  [inverse==forward, XOR involution]
  const int srow = tid >> 3;              // row within 32-row group; +32*i later? no:
  // NOTE: c>>3 for c=i*256+tid -> i*32 + (tid>>3); slot=(tid&7)^(row&7)
  for (int bk0 = 0; bk0 < K; bk0 += 64) {
    __syncthreads();
#pragma unroll
    for (int i = 0; i < 4; ++i) {
      const int row = i * 32 + srow;
      const int slot = (tid & 7) ^ (row & 7);
      const size_t goffA = (size_t)(bm0 + row) * K + bk0 + slot * 8;
      const size_t goffB = (size_t)(bn0 + row) * K + bk0 + slot * 8;
      u16* ldsbase_a = &As[(size_t)(i * 256 + w * 64) * 8];
      u16* ldsbase_b = &Bs[(size_t)(i * 256 + w * 64) * 8];
      lds16(ldsbase_a, &A[goffA]);
      lds16(ldsbase_b, &B[goffB]);
    }
    __syncthreads();
#pragma unroll
    for (int kk = 0; kk < 64; kk += 32) {
      bf16x8 af[4], bfv[4];
#pragma unroll
      for (int m = 0; m < 4; ++m) {
        const int row = wr + m * 16 + fr;
        const int slot = ((kk >> 3) + fg) ^ (row & 7);
        af[m] = *(const bf16x8*)&As[row * 64 + slot * 8];
      }
#pragma unroll
      for (int n = 0; n < 4; ++n) {
        const int row = wc + n * 16 + fr;
        const int slot = ((kk >> 3) + fg) ^ (row & 7);
        bfv[n] = *(const bf16x8*)&Bs[row * 64 + slot * 8];
      }
#pragma unroll
      for (int m = 0; m < 4; ++m)
#pragma unroll
        for (int n = 0; n < 4; ++n)
          acc[m][n] = MFMA16(af[m], bfv[n], acc[m][n]);
    }
  }

#pragma unroll
  for (int n = 0; n < 4; ++n) {
    const int col = bn0 + wc + n * 16 + fr;
    const float bv = bias ? bias[col] : 0.0f;
#pragma unroll
    for (int m = 0; m < 4; ++m) {
#pragma unroll
      for (int r = 0; r < 4; ++r) {
        const int row = bm0 + wr + m * 16 + fg * 4 + r;
        float v = acc[m][n][r] + bv;
        if (MODE == 1) v = gelu_f(v);
        const size_t off = (size_t)row * N + col;
        if (MODE == 2) {
          const float nv = resid[off] + v;
          resid[off] = nv;
          if (mirror) mirror[off] = f2b(nv);
        } else if (MODE == 3) {
          outf[off] = v;
        } else {
          outb[off] = f2b(v);
        }
      }
    }
  }
}

// ===== fallback GEMM (B is f32, converted during staging) — round-2 proven ===
template <int MODE>
__global__ __launch_bounds__(256) void gemm_bt(
    const u16* __restrict__ A, const float* __restrict__ B,
    const float* __restrict__ bias, u16* __restrict__ outb,
    float* __restrict__ outf, float* __restrict__ resid,
    u16* __restrict__ mirror, int N, int K) {
  __shared__ alignas(16) u16 As[128 * 64];
  __shared__ alignas(16) u16 Bs[128 * 64];
  const int tid = threadIdx.x;
  const int lane = tid & 63;
  const int w = tid >> 6;
  const int wr = (w >> 1) * 64;
  const int wc = (w & 1) * 64;
  const int fr = lane & 15;
  const int fg = lane >> 4;
  const int bn0 = blockIdx.x * 128;
  const int bm0 = blockIdx.y * 128;

  f32x4 acc[4][4] = {};

  for (int bk0 = 0; bk0 < K; bk0 += 64) {
    __syncthreads();
#pragma unroll
    for (int i = 0; i < 4; ++i) {
      const int c = i * 256 + tid;
      const int row = c >> 3;
      const int e0 = (c & 7) * 8;
      *(u32x4*)&As[row * 64 + e0] =
          *(const u32x4*)&A[(size_t)(bm0 + row) * K + bk0 + e0];
    }
#pragma unroll
    for (int i = 0; i < 8; ++i) {
      const int c = i * 256 + tid;
      const int row = c >> 4;
      const int e0 = (c & 15) * 4;
      const f32x4 fv = *(const f32x4*)&B[(size_t)(bn0 + row) * K + bk0 + e0];
      u16x4 pv;
#pragma unroll
      for (int j = 0; j < 4; ++j) pv[j] = f2b(fv[j]);
      *(u16x4*)&Bs[row * 64 + e0] = pv;
    }
    __syncthreads();
#pragma unroll
    for (int kk = 0; kk < 64; kk += 32) {
      bf16x8 af[4], bfv[4];
#pragma unroll
      for (int m = 0; m < 4; ++m)
        af[m] = *(const bf16x8*)&As[(wr + m * 16 + fr) * 64 + kk + fg * 8];
#pragma unroll
      for (int n = 0; n < 4; ++n)
        bfv[n] = *(const bf16x8*)&Bs[(wc + n * 16 + fr) * 64 + kk + fg * 8];
#pragma unroll
      for (int m = 0; m < 4; ++m)
#pragma unroll
        for (int n = 0; n < 4; ++n)
          acc[m][n] = MFMA16(af[m], bfv[n], acc[m][n]);
    }
  }

#pragma unroll
  for (int n = 0; n < 4; ++n) {
    const int col = bn0 + wc + n * 16 + fr;
    const float bv = bias ? bias[col] : 0.0f;
#pragma unroll
    for (int m = 0; m < 4; ++m) {
#pragma unroll
      for (int r = 0; r < 4; ++r) {
        const int row = bm0 + wr + m * 16 + fg * 4 + r;
        float v = acc[m][n][r] + bv;
        if (MODE == 1) v = gelu_f(v);
        const size_t off = (size_t)row * N + col;
        if (MODE == 2) {
          const float nv = resid[off] + v;
          resid[off] = nv;
          if (mirror) mirror[off] = f2b(nv);
        } else if (MODE == 3) {
          outf[off] = v;
        } else {
          outb[off] = f2b(v);
        }
      }
    }
  }
}

// ---------------- fused attention (no causal mask) ---------------------------
__global__ __launch_bounds__(256) void attn_kernel(
    const u16* __restrict__ qkv, u16* __restrict__ y) {
  __shared__ alignas(16) u16 Ks[32 * 64];     // K tile  [32 keys][64]
  __shared__ alignas(16) u16 VTs[64 * 32];    // V tile^T [64 d][32 keys]
  __shared__ alignas(16) u16 Ps[4][16 * 32];  // per-wave P [16 q][32 keys]
  const int tid = threadIdx.x;
  const int lane = tid & 63;
  const int w = tid >> 6;
  const int fr = lane & 15;
  const int fg = lane >> 4;
  const int qb = blockIdx.x;
  const int hh = blockIdx.y;
  const int bb = blockIdx.z;
  const size_t tb = (size_t)bb * 2048 * 2304;
  const int q0 = qb * 64 + w * 16;

  const bf16x8 qf0 =
      *(const bf16x8*)&qkv[tb + (size_t)(q0 + fr) * 2304 + hh * 64 + fg * 8];
  const bf16x8 qf1 =
      *(const bf16x8*)&qkv[tb + (size_t)(q0 + fr) * 2304 + hh * 64 + 32 + fg * 8];

  f32x4 oacc[4] = {};
  float mrow[4] = {-INFINITY, -INFINITY, -INFINITY, -INFINITY};
  float lrow[4] = {0.f, 0.f, 0.f, 0.f};

  const int skey = tid >> 3;
  const int se0 = (tid & 7) * 8;

  for (int kt = 0; kt < 2048; kt += 32) {
    __syncthreads();
    {
      const size_t rbase = tb + (size_t)(kt + skey) * 2304 + hh * 64 + se0;
      *(u32x4*)&Ks[skey * 64 + se0] = *(const u32x4*)&qkv[rbase + 768];
      union { u32x4 v; u16 s[8]; } tmp;
      tmp.v = *(const u32x4*)&qkv[rbase + 1536];
#pragma unroll
      for (int j = 0; j < 8; ++j) VTs[(se0 + j) * 32 + skey] = tmp.s[j];
    }
    __syncthreads();

    f32x4 s0 = {}, s1 = {};
    {
      const bf16x8 k00 = *(const bf16x8*)&Ks[fr * 64 + fg * 8];
      const bf16x8 k01 = *(const bf16x8*)&Ks[fr * 64 + 32 + fg * 8];
      const bf16x8 k10 = *(const bf16x8*)&Ks[(16 + fr) * 64 + fg * 8];
      const bf16x8 k11 = *(const bf16x8*)&Ks[(16 + fr) * 64 + 32 + fg * 8];
      s0 = MFMA16(qf0, k00, s0);
      s0 = MFMA16(qf1, k01, s0);
      s1 = MFMA16(qf0, k10, s1);
      s1 = MFMA16(qf1, k11, s1);
    }

    float alpha[4];
#pragma unroll
    for (int r = 0; r < 4; ++r) {
      const float a = s0[r] * 0.125f;
      const float c = s1[r] * 0.125f;
      float mx = fmaxf(a, c);
      mx = fmaxf(mx, __shfl_xor(mx, 1));
      mx = fmaxf(mx, __shfl_xor(mx, 2));
      mx = fmaxf(mx, __shfl_xor(mx, 4));
      mx = fmaxf(mx, __shfl_xor(mx, 8));
      const float mn = fmaxf(mrow[r], mx);
      const float al = __expf(mrow[r] - mn);
      const float p0 = __expf(a - mn);
      const float p1 = __expf(c - mn);
      float ps = p0 + p1;
      ps += __shfl_xor(ps, 1);
      ps += __shfl_xor(ps, 2);
      ps += __shfl_xor(ps, 4);
      ps += __shfl_xor(ps, 8);
      lrow[r] = lrow[r] * al + ps;
      mrow[r] = mn;
      alpha[r] = al;
      Ps[w][(fg * 4 + r) * 32 + fr] = f2b(p0);
      Ps[w][(fg * 4 + r) * 32 + 16 + fr] = f2b(p1);
    }
#pragma unroll
    for (int db = 0; db < 4; ++db)
#pragma unroll
      for (int r = 0; r < 4; ++r) oacc[db][r] *= alpha[r];

    const bf16x8 pa = *(const bf16x8*)&Ps[w][fr * 32 + fg * 8];
#pragma unroll
    for (int db = 0; db < 4; ++db) {
      const bf16x8 vb = *(const bf16x8*)&VTs[(db * 16 + fr) * 32 + fg * 8];
      oacc[db] = MFMA16(pa, vb, oacc[db]);
    }
  }

#pragma unroll
  for (int db = 0; db < 4; ++db) {
#pragma unroll
    for (int r = 0; r < 4; ++r) {
      const int row = q0 + fg * 4 + r;
      y[(size_t)(bb * 2048 + row) * 768 + hh * 64 + db * 16 + fr] =
          f2b(oacc[db][r] / lrow[r]);
    }
  }
}

// ---------------- launcher ---------------------------------------------------
extern "C" void kernel_launch(void* const* d_in, const int* in_sizes, int n_in,
                              void* d_out, int out_size, void* d_ws,
                              size_t ws_size, hipStream_t stream) {
  const int*   idx   = (const int*)d_in[0];
  const float* tok   = (const float*)d_in[1];
  const float* pos   = (const float*)d_in[2];
  const float* attnw = (const float*)d_in[3];
  const float* attnb = (const float*)d_in[4];
  const float* projw = (const float*)d_in[5];
  const float* projb = (const float*)d_in[6];
  const float* ln1g  = (const float*)d_in[7];
  const float* ln1b  = (const float*)d_in[8];
  const float* ln2g  = (const float*)d_in[9];
  const float* ln2b  = (const float*)d_in[10];
  const float* fc1w  = (const float*)d_in[11];
  const float* fc1b  = (const float*)d_in[12];
  const float* fc2w  = (const float*)d_in[13];
  const float* fc2b  = (const float*)d_in[14];
  const float* decw  = (const float*)d_in[15];

  char* ws = (char*)d_ws;
  float* x = (float*)(ws);                      // [0, 12.58MB)   4096*768 f32
  u16* h   = (u16*)(ws + 12582912);             // 4096*768 bf16
  u16* qkv = (u16*)(ws + 18874368);             // 4096*2304 bf16
  u16* y   = (u16*)(ws + 37748736);             // 4096*768 bf16
  u16* h2  = (u16*)(ws + 18874368);             // alias qkv+y: 4096*3072 bf16

  // bf16 weight arena
  const size_t WB0 = 44040192;
  u16* attnw_b = (u16*)(ws + WB0);                     // 10,616,832 el
  u16* projw_b = (u16*)(ws + WB0 + 21233664);          //  3,538,944 el
  u16* fc1w_b  = (u16*)(ws + WB0 + 28311552);          // 14,155,776 el
  u16* fc2w_b  = (u16*)(ws + WB0 + 56623104);          // 14,155,776 el
  u16* decw_b  = (u16*)(ws + WB0 + 84934656);          // 24,576,000 el
  const size_t NEED = WB0 + 84934656 + 49152000;       // 178,126,848 B

  embed_kernel<<<4096, 256, 0, stream>>>(idx, tok, pos, x);

  if (ws_size >= NEED) {
    conv_bf16_kernel<<<2048, 256, 0, stream>>>(attnw, attnw_b, 10616832 / 8);
    conv_bf16_kernel<<<2048, 256, 0, stream>>>(projw, projw_b, 3538944 / 8);
    conv_bf16_kernel<<<2048, 256, 0, stream>>>(fc1w, fc1w_b, 14155776 / 8);
    conv_bf16_kernel<<<2048, 256, 0, stream>>>(fc2w, fc2w_b, 14155776 / 8);
    conv_bf16_kernel<<<2048, 256, 0, stream>>>(decw, decw_b, 24576000 / 8);

    for (int l = 0; l < 6; ++l) {
      ln_kernel<<<4096, 256, 0, stream>>>(x, ln1g + l * 768, ln1b + l * 768, h);
      gemm_bb<0, 0><<<dim3(18, 32), 256, 0, stream>>>(
          h, attnw_b + (size_t)l * 2304 * 768, attnb + l * 2304, qkv, nullptr,
          nullptr, nullptr, 2304, 768);
      attn_kernel<<<dim3(32, 12, 2), 256, 0, stream>>>(qkv, y);
      gemm_bb<2, 0><<<dim3(6, 32), 256, 0, stream>>>(
          y, projw_b + (size_t)l * 768 * 768, projb + l * 768, nullptr, nullptr,
          x, nullptr, 768, 768);
      ln_kernel<<<4096, 256, 0, stream>>>(x, ln2g + l * 768, ln2b + l * 768, h);
      gemm_bb<1, 0><<<dim3(24, 32), 256, 0, stream>>>(
          h, fc1w_b + (size_t)l * 3072 * 768, fc1b + l * 3072, h2, nullptr,
          nullptr, nullptr, 3072, 768);
      gemm_bb<2, 0><<<dim3(6, 32), 256, 0, stream>>>(
          h2, fc2w_b + (size_t)l * 768 * 3072, fc2b + l * 768, nullptr, nullptr,
          x, (l == 5) ? h : nullptr, 768, 3072);
    }
    // decoder: M-fast grid for B-panel L2 reuse (B bf16 = 49 MB, A = 6.3 MB)
    gemm_bb<3, 1><<<dim3(32, 250), 256, 0, stream>>>(
        h, decw_b, nullptr, nullptr, (float*)d_out, nullptr, nullptr, 32000,
        768);
  } else {
    // fallback: round-2 proven path (f32 weights converted during staging)
    for (int l = 0; l < 6; ++l) {
      ln_kernel<<<4096, 256, 0, stream>>>(x, ln1g + l * 768, ln1b + l * 768, h);
      gemm_bt<0><<<dim3(18, 32), 256, 0, stream>>>(
          h, attnw + (size_t)l * 2304 * 768, attnb + l * 2304, qkv, nullptr,
          nullptr, nullptr, 2304, 768);
      attn_kernel<<<dim3(32, 12, 2), 256, 0, stream>>>(qkv, y);
      gemm_bt<2><<<dim3(6, 32), 256, 0, stream>>>(
          y, projw + (size_t)l * 768 * 768, projb + l * 768, nullptr, nullptr,
          x, nullptr, 768, 768);
      ln_kernel<<<4096, 256, 0, stream>>>(x, ln2g + l * 768, ln2b + l * 768, h);
      gemm_bt<1><<<dim3(24, 32), 256, 0, stream>>>(
          h, fc1w + (size_t)l * 3072 * 768, fc1b + l * 3072, h2, nullptr,
          nullptr, nullptr, 3072, 768);
      gemm_bt<2><<<dim3(6, 32), 256, 0, stream>>>(
          h2, fc2w + (size_t)l * 768 * 3072, fc2b + l * 768, nullptr, nullptr,
          x, (l == 5) ? h : nullptr, 768, 3072);
    }
    gemm_bt<3><<<dim3(250, 32), 256, 0, stream>>>(
        h, decw, nullptr, nullptr, (float*)d_out, nullptr, nullptr, 32000, 768);
  }
}

// Round 4
// 2008.623 us; speedup vs baseline: 1.5938x; 1.3186x over previous
//
#include <hip/hip_runtime.h>
#include <hip/hip_bf16.h>
#include <stdint.h>

// VanillaTransformer: V=32000 S=2048 D=768 H=12 HD=64 L=6, batch=2 -> 4096 tokens
// Inputs: f32 (+ idx int32). Output: f32 logits [2,2048,32000].
// Fast path: weights pre-converted f32->bf16; GEMMs + attention stage via
// global_load_lds width-16 with XOR slot swizzle (conflict-free, verified r3).

typedef unsigned short u16;
typedef __attribute__((ext_vector_type(8))) __bf16 bf16x8;
typedef __attribute__((ext_vector_type(4))) float f32x4;
typedef __attribute__((ext_vector_type(4))) unsigned int u32x4;
typedef __attribute__((ext_vector_type(4))) unsigned short u16x4;
typedef __attribute__((ext_vector_type(8))) unsigned short u16x8;

#define MFMA16(a, b, c) __builtin_amdgcn_mfma_f32_16x16x32_bf16((a), (b), (c), 0, 0, 0)

__device__ __forceinline__ float b2f(u16 u) {
  union { unsigned int i; float f; } x; x.i = ((unsigned int)u) << 16; return x.f;
}
__device__ __forceinline__ u16 f2b(float f) {  // round-to-nearest-even
  union { float f; unsigned int i; } x; x.f = f;
  unsigned int r = x.i + 0x7fffu + ((x.i >> 16) & 1u);
  return (u16)(r >> 16);
}
__device__ __forceinline__ float gelu_f(float v) {  // tanh-approx (jax default)
  const float t = 0.7978845608028654f * (v + 0.044715f * v * v * v);
  const float e = __expf(-2.f * fabsf(t));
  float th = (1.f - e) / (1.f + e);
  th = (t < 0.f) ? -th : th;
  return 0.5f * v * (1.f + th);
}
// async global->LDS, 16B per lane; LDS base wave-uniform, HW adds lane*16B.
__device__ __forceinline__ void lds16(u16* l, const u16* g) {
  __builtin_amdgcn_global_load_lds(
      (const __attribute__((address_space(1))) unsigned int*)g,
      (__attribute__((address_space(3))) unsigned int*)l, 16, 0, 0);
}

// ---------------- f32 -> bf16 conversion (weights) ---------------------------
__global__ __launch_bounds__(256) void conv_bf16_kernel(
    const float* __restrict__ src, u16* __restrict__ dst, int n8) {
  int i = blockIdx.x * 256 + threadIdx.x;
  const int stride = gridDim.x * 256;
  for (; i < n8; i += stride) {
    const f32x4 a = *(const f32x4*)&src[(size_t)i * 8];
    const f32x4 b = *(const f32x4*)&src[(size_t)i * 8 + 4];
    u16x8 p;
#pragma unroll
    for (int j = 0; j < 4; ++j) { p[j] = f2b(a[j]); p[4 + j] = f2b(b[j]); }
    *(u16x8*)&dst[(size_t)i * 8] = p;
  }
}

// ---------------- embedding --------------------------------------------------
__global__ __launch_bounds__(256) void embed_kernel(
    const int* __restrict__ idx, const float* __restrict__ tok,
    const float* __restrict__ pos, float* __restrict__ x) {
  const int t = blockIdx.x;
  const int s = t & 2047;
  const int tid = threadIdx.x;
  const size_t to = (size_t)idx[t] * 768;
  const size_t po = (size_t)s * 768;
  float* xr = x + (size_t)t * 768;
#pragma unroll
  for (int i = 0; i < 3; ++i) {
    const int d = tid + i * 256;
    xr[d] = tok[to + d] + pos[po + d];
  }
}

// ---------------- LayerNorm: f32 in -> bf16 out ------------------------------
__global__ __launch_bounds__(256) void ln_kernel(
    const float* __restrict__ x, const float* __restrict__ g,
    const float* __restrict__ b, u16* __restrict__ out) {
  __shared__ float red[8];
  const int row = blockIdx.x;
  const int tid = threadIdx.x;
  const float* xr = x + (size_t)row * 768;
  const float v0 = xr[tid], v1 = xr[tid + 256], v2 = xr[tid + 512];
  float s = v0 + v1 + v2;
#pragma unroll
  for (int m = 1; m < 64; m <<= 1) s += __shfl_xor(s, m);
  const int w = tid >> 6, lane = tid & 63;
  if (lane == 0) red[w] = s;
  __syncthreads();
  const float mu = (red[0] + red[1] + red[2] + red[3]) * (1.f / 768.f);
  const float d0 = v0 - mu, d1 = v1 - mu, d2 = v2 - mu;
  float q = d0 * d0 + d1 * d1 + d2 * d2;
#pragma unroll
  for (int m = 1; m < 64; m <<= 1) q += __shfl_xor(q, m);
  if (lane == 0) red[4 + w] = q;
  __syncthreads();
  const float var = (red[4] + red[5] + red[6] + red[7]) * (1.f / 768.f);
  const float rs = rsqrtf(var + 1e-5f);
  u16* orow = out + (size_t)row * 768;
  orow[tid]       = f2b(d0 * rs * g[tid]       + b[tid]);
  orow[tid + 256] = f2b(d1 * rs * g[tid + 256] + b[tid + 256]);
  orow[tid + 512] = f2b(d2 * rs * g[tid + 512] + b[tid + 512]);
}

// ===== fast GEMM: C[M,N] = A[M,K](bf16) * B[N,K](bf16)^T, lds-direct staging =
// MODE 0: outb=bf16(acc+bias)  1: +gelu  2: resid+= (f32), opt bf16 mirror
// MODE 3: outf = acc (f32, nontemporal)
template <int MODE, int MFAST>
__global__ __launch_bounds__(256) void gemm_bb(
    const u16* __restrict__ A, const u16* __restrict__ B,
    const float* __restrict__ bias, u16* __restrict__ outb,
    float* __restrict__ outf, float* __restrict__ resid,
    u16* __restrict__ mirror, int N, int K) {
  __shared__ alignas(16) u16 As[128 * 64];
  __shared__ alignas(16) u16 Bs[128 * 64];
  const int tid = threadIdx.x;
  const int lane = tid & 63;
  const int w = tid >> 6;
  const int wr = (w >> 1) * 64;
  const int wc = (w & 1) * 64;
  const int fr = lane & 15;
  const int fg = lane >> 4;
  const int bn0 = (MFAST ? blockIdx.y : blockIdx.x) * 128;
  const int bm0 = (MFAST ? blockIdx.x : blockIdx.y) * 128;

  f32x4 acc[4][4] = {};
  const int srow = tid >> 3;

  for (int bk0 = 0; bk0 < K; bk0 += 64) {
    __syncthreads();
#pragma unroll
    for (int i = 0; i < 4; ++i) {
      const int row = i * 32 + srow;
      const int slot = (tid & 7) ^ (row & 7);
      lds16(&As[(size_t)(i * 256 + w * 64) * 8],
            &A[(size_t)(bm0 + row) * K + bk0 + slot * 8]);
      lds16(&Bs[(size_t)(i * 256 + w * 64) * 8],
            &B[(size_t)(bn0 + row) * K + bk0 + slot * 8]);
    }
    __syncthreads();
#pragma unroll
    for (int kk = 0; kk < 64; kk += 32) {
      bf16x8 af[4], bfv[4];
#pragma unroll
      for (int m = 0; m < 4; ++m) {
        const int row = wr + m * 16 + fr;
        const int slot = ((kk >> 3) + fg) ^ (row & 7);
        af[m] = *(const bf16x8*)&As[row * 64 + slot * 8];
      }
#pragma unroll
      for (int n = 0; n < 4; ++n) {
        const int row = wc + n * 16 + fr;
        const int slot = ((kk >> 3) + fg) ^ (row & 7);
        bfv[n] = *(const bf16x8*)&Bs[row * 64 + slot * 8];
      }
#pragma unroll
      for (int m = 0; m < 4; ++m)
#pragma unroll
        for (int n = 0; n < 4; ++n)
          acc[m][n] = MFMA16(af[m], bfv[n], acc[m][n]);
    }
  }

#pragma unroll
  for (int n = 0; n < 4; ++n) {
    const int col = bn0 + wc + n * 16 + fr;
    const float bv = bias ? bias[col] : 0.0f;
#pragma unroll
    for (int m = 0; m < 4; ++m) {
#pragma unroll
      for (int r = 0; r < 4; ++r) {
        const int row = bm0 + wr + m * 16 + fg * 4 + r;
        float v = acc[m][n][r] + bv;
        if (MODE == 1) v = gelu_f(v);
        const size_t off = (size_t)row * N + col;
        if (MODE == 2) {
          const float nv = resid[off] + v;
          resid[off] = nv;
          if (mirror) mirror[off] = f2b(nv);
        } else if (MODE == 3) {
          __builtin_nontemporal_store(v, &outf[off]);
        } else {
          outb[off] = f2b(v);
        }
      }
    }
  }
}

// ===== fallback GEMM (B is f32, converted during staging) ====================
template <int MODE>
__global__ __launch_bounds__(256) void gemm_bt(
    const u16* __restrict__ A, const float* __restrict__ B,
    const float* __restrict__ bias, u16* __restrict__ outb,
    float* __restrict__ outf, float* __restrict__ resid,
    u16* __restrict__ mirror, int N, int K) {
  __shared__ alignas(16) u16 As[128 * 64];
  __shared__ alignas(16) u16 Bs[128 * 64];
  const int tid = threadIdx.x;
  const int lane = tid & 63;
  const int w = tid >> 6;
  const int wr = (w >> 1) * 64;
  const int wc = (w & 1) * 64;
  const int fr = lane & 15;
  const int fg = lane >> 4;
  const int bn0 = blockIdx.x * 128;
  const int bm0 = blockIdx.y * 128;

  f32x4 acc[4][4] = {};

  for (int bk0 = 0; bk0 < K; bk0 += 64) {
    __syncthreads();
#pragma unroll
    for (int i = 0; i < 4; ++i) {
      const int c = i * 256 + tid;
      const int row = c >> 3;
      const int e0 = (c & 7) * 8;
      *(u32x4*)&As[row * 64 + e0] =
          *(const u32x4*)&A[(size_t)(bm0 + row) * K + bk0 + e0];
    }
#pragma unroll
    for (int i = 0; i < 8; ++i) {
      const int c = i * 256 + tid;
      const int row = c >> 4;
      const int e0 = (c & 15) * 4;
      const f32x4 fv = *(const f32x4*)&B[(size_t)(bn0 + row) * K + bk0 + e0];
      u16x4 pv;
#pragma unroll
      for (int j = 0; j < 4; ++j) pv[j] = f2b(fv[j]);
      *(u16x4*)&Bs[row * 64 + e0] = pv;
    }
    __syncthreads();
#pragma unroll
    for (int kk = 0; kk < 64; kk += 32) {
      bf16x8 af[4], bfv[4];
#pragma unroll
      for (int m = 0; m < 4; ++m)
        af[m] = *(const bf16x8*)&As[(wr + m * 16 + fr) * 64 + kk + fg * 8];
#pragma unroll
      for (int n = 0; n < 4; ++n)
        bfv[n] = *(const bf16x8*)&Bs[(wc + n * 16 + fr) * 64 + kk + fg * 8];
#pragma unroll
      for (int m = 0; m < 4; ++m)
#pragma unroll
        for (int n = 0; n < 4; ++n)
          acc[m][n] = MFMA16(af[m], bfv[n], acc[m][n]);
    }
  }

#pragma unroll
  for (int n = 0; n < 4; ++n) {
    const int col = bn0 + wc + n * 16 + fr;
    const float bv = bias ? bias[col] : 0.0f;
#pragma unroll
    for (int m = 0; m < 4; ++m) {
#pragma unroll
      for (int r = 0; r < 4; ++r) {
        const int row = bm0 + wr + m * 16 + fg * 4 + r;
        float v = acc[m][n][r] + bv;
        if (MODE == 1) v = gelu_f(v);
        const size_t off = (size_t)row * N + col;
        if (MODE == 2) {
          const float nv = resid[off] + v;
          resid[off] = nv;
          if (mirror) mirror[off] = f2b(nv);
        } else if (MODE == 3) {
          __builtin_nontemporal_store(v, &outf[off]);
        } else {
          outb[off] = f2b(v);
        }
      }
    }
  }
}

// ---------------- V transpose: qkv V-part -> vt[bh][d][s] --------------------
// grid (32 s-tiles, 12 h, 2 b), 256 threads; 64x64 tile via padded LDS.
__global__ __launch_bounds__(256) void vtrans_kernel(
    const u16* __restrict__ qkv, u16* __restrict__ vt) {
  __shared__ u16 tile[64][72];  // +8 pad: row stride 144B (16B-aligned, odd banks)
  const int tid = threadIdx.x;
  const int s0 = blockIdx.x * 64;
  const int hh = blockIdx.y;
  const int bb = blockIdx.z;
  const size_t tb = (size_t)bb * 2048 * 2304;
#pragma unroll
  for (int i = 0; i < 2; ++i) {
    const int c = i * 256 + tid;
    const int sl = c >> 3;
    const int d0 = (c & 7) * 8;
    *(u16x8*)&tile[sl][d0] =
        *(const u16x8*)&qkv[tb + (size_t)(s0 + sl) * 2304 + 1536 + hh * 64 + d0];
  }
  __syncthreads();
  const size_t vtb = (size_t)((bb * 12 + hh) * 64) * 2048;
#pragma unroll
  for (int i = 0; i < 2; ++i) {
    const int c = i * 256 + tid;
    const int d = c >> 3;
    const int so = (c & 7) * 8;
    u16x8 p;
#pragma unroll
    for (int j = 0; j < 8; ++j) p[j] = tile[so + j][d];
    *(u16x8*)&vt[vtb + (size_t)d * 2048 + s0 + so] = p;
  }
}

// ---------------- fused attention v2 (no causal mask) ------------------------
// grid (32 qb, 12 h, 2 b), 256 thr / 4 waves; wave = 16 q-rows; KVBLK=64.
// K from qkv (row-major [key][64]); V^T from vt ([d][s]). Both staged via
// lds16 with XOR slot swizzle; double-buffered (stage t+1 overlaps compute t).
__global__ __launch_bounds__(256) void attn_kernel(
    const u16* __restrict__ qkv, const u16* __restrict__ vt,
    u16* __restrict__ y) {
  __shared__ alignas(16) u16 Ks[2][64 * 64];   // 16 KB
  __shared__ alignas(16) u16 VTs[2][64 * 64];  // 16 KB
  __shared__ alignas(16) u16 Ps[4][16 * 64];   //  8 KB (per-wave P, swizzled)
  const int tid = threadIdx.x;
  const int lane = tid & 63;
  const int w = tid >> 6;
  const int fr = lane & 15;
  const int fg = lane >> 4;
  const int hh = blockIdx.y;
  const int bb = blockIdx.z;
  const size_t tb = (size_t)bb * 2048 * 2304;
  const size_t vtb = (size_t)((bb * 12 + hh) * 64) * 2048;
  const int q0 = blockIdx.x * 64 + w * 16;

  const bf16x8 qf0 =
      *(const bf16x8*)&qkv[tb + (size_t)(q0 + fr) * 2304 + hh * 64 + fg * 8];
  const bf16x8 qf1 =
      *(const bf16x8*)&qkv[tb + (size_t)(q0 + fr) * 2304 + hh * 64 + 32 + fg * 8];

  f32x4 oacc[4] = {};
  float mrow[4] = {-INFINITY, -INFINITY, -INFINITY, -INFINITY};
  float lrow[4] = {0.f, 0.f, 0.f, 0.f};

  // staging geometry: 512 chunks of 16B per 64x64 tile; 2 chunks/thread.
  const int chunkrow = lane >> 3;   // + (i*4+w)*8
  const int chunkslot = lane & 7;

  auto stage = [&](int buf, int kt) {
#pragma unroll
    for (int i = 0; i < 2; ++i) {
      const int row = (i * 4 + w) * 8 + chunkrow;
      const int slot = chunkslot ^ (row & 7);
      lds16(&Ks[buf][(i * 4 + w) * 512],
            &qkv[tb + (size_t)(kt + row) * 2304 + 768 + hh * 64 + slot * 8]);
      lds16(&VTs[buf][(i * 4 + w) * 512],
            &vt[vtb + (size_t)row * 2048 + kt + slot * 8]);
    }
  };

  stage(0, 0);
  int cur = 0;
  for (int kt = 0; kt < 2048; kt += 64) {
    __syncthreads();  // stage(cur) landed; all prior reads of cur^1 done
    if (kt + 64 < 2048) stage(cur ^ 1, kt + 64);

    // QK^T: S[q=4fg+r][key=kb*16+fr]
    f32x4 s[4] = {};
#pragma unroll
    for (int kb = 0; kb < 4; ++kb) {
      const int row = kb * 16 + fr;
      const int sl0 = (fg) ^ (row & 7);
      const int sl1 = (4 + fg) ^ (row & 7);
      const bf16x8 k0 = *(const bf16x8*)&Ks[cur][row * 64 + sl0 * 8];
      const bf16x8 k1 = *(const bf16x8*)&Ks[cur][row * 64 + sl1 * 8];
      s[kb] = MFMA16(qf0, k0, s[kb]);
      s[kb] = MFMA16(qf1, k1, s[kb]);
    }

    float alpha[4];
#pragma unroll
    for (int r = 0; r < 4; ++r) {
      float v[4];
#pragma unroll
      for (int kb = 0; kb < 4; ++kb) v[kb] = s[kb][r] * 0.125f;
      float mx = fmaxf(fmaxf(v[0], v[1]), fmaxf(v[2], v[3]));
      mx = fmaxf(mx, __shfl_xor(mx, 1));
      mx = fmaxf(mx, __shfl_xor(mx, 2));
      mx = fmaxf(mx, __shfl_xor(mx, 4));
      mx = fmaxf(mx, __shfl_xor(mx, 8));
      const float mn = fmaxf(mrow[r], mx);
      const float al = __expf(mrow[r] - mn);
      float p[4];
#pragma unroll
      for (int kb = 0; kb < 4; ++kb) p[kb] = __expf(v[kb] - mn);
      float ps = (p[0] + p[1]) + (p[2] + p[3]);
      ps += __shfl_xor(ps, 1);
      ps += __shfl_xor(ps, 2);
      ps += __shfl_xor(ps, 4);
      ps += __shfl_xor(ps, 8);
      lrow[r] = lrow[r] * al + ps;
      mrow[r] = mn;
      alpha[r] = al;
      const int q = fg * 4 + r;
#pragma unroll
      for (int kb = 0; kb < 4; ++kb) {
        const int kg = kb * 2 + (fr >> 3);
        Ps[w][q * 64 + ((kg ^ (q & 7)) << 3) + (fr & 7)] = f2b(p[kb]);
      }
    }
#pragma unroll
    for (int db = 0; db < 4; ++db)
#pragma unroll
      for (int r = 0; r < 4; ++r) oacc[db][r] *= alpha[r];

    // PV: O[q][d] += P[q][k] V[k][d]; A=P rows (wave-private LDS), B=V^T rows.
#pragma unroll
    for (int kh = 0; kh < 2; ++kh) {
      const bf16x8 pa =
          *(const bf16x8*)&Ps[w][fr * 64 + (((kh * 4 + fg) ^ (fr & 7)) << 3)];
#pragma unroll
      for (int db = 0; db < 4; ++db) {
        const int row = db * 16 + fr;
        const int slot = (kh * 4 + fg) ^ (row & 7);
        const bf16x8 vb = *(const bf16x8*)&VTs[cur][row * 64 + slot * 8];
        oacc[db] = MFMA16(pa, vb, oacc[db]);
      }
    }
    cur ^= 1;
  }

#pragma unroll
  for (int db = 0; db < 4; ++db) {
#pragma unroll
    for (int r = 0; r < 4; ++r) {
      const int row = q0 + fg * 4 + r;
      y[(size_t)(bb * 2048 + row) * 768 + hh * 64 + db * 16 + fr] =
          f2b(oacc[db][r] / lrow[r]);
    }
  }
}

// ---------------- launcher ---------------------------------------------------
extern "C" void kernel_launch(void* const* d_in, const int* in_sizes, int n_in,
                              void* d_out, int out_size, void* d_ws,
                              size_t ws_size, hipStream_t stream) {
  const int*   idx   = (const int*)d_in[0];
  const float* tok   = (const float*)d_in[1];
  const float* pos   = (const float*)d_in[2];
  const float* attnw = (const float*)d_in[3];
  const float* attnb = (const float*)d_in[4];
  const float* projw = (const float*)d_in[5];
  const float* projb = (const float*)d_in[6];
  const float* ln1g  = (const float*)d_in[7];
  const float* ln1b  = (const float*)d_in[8];
  const float* ln2g  = (const float*)d_in[9];
  const float* ln2b  = (const float*)d_in[10];
  const float* fc1w  = (const float*)d_in[11];
  const float* fc1b  = (const float*)d_in[12];
  const float* fc2w  = (const float*)d_in[13];
  const float* fc2b  = (const float*)d_in[14];
  const float* decw  = (const float*)d_in[15];

  char* ws = (char*)d_ws;
  float* x = (float*)(ws);                      // 4096*768 f32
  u16* h   = (u16*)(ws + 12582912);             // 4096*768 bf16
  u16* qkv = (u16*)(ws + 18874368);             // 4096*2304 bf16
  u16* y   = (u16*)(ws + 37748736);             // 4096*768 bf16
  u16* h2  = (u16*)(ws + 18874368);             // alias qkv+y (MLP phase)
  u16* vt  = h;  // alias: h is dead between qkv-GEMM and ln2 (attn phase)

  const size_t WB0 = 44040192;
  u16* attnw_b = (u16*)(ws + WB0);
  u16* projw_b = (u16*)(ws + WB0 + 21233664);
  u16* fc1w_b  = (u16*)(ws + WB0 + 28311552);
  u16* fc2w_b  = (u16*)(ws + WB0 + 56623104);
  u16* decw_b  = (u16*)(ws + WB0 + 84934656);
  const size_t NEED = WB0 + 84934656 + 49152000;  // 178,126,848 B

  embed_kernel<<<4096, 256, 0, stream>>>(idx, tok, pos, x);

  if (ws_size >= NEED) {
    conv_bf16_kernel<<<2048, 256, 0, stream>>>(attnw, attnw_b, 10616832 / 8);
    conv_bf16_kernel<<<2048, 256, 0, stream>>>(projw, projw_b, 3538944 / 8);
    conv_bf16_kernel<<<2048, 256, 0, stream>>>(fc1w, fc1w_b, 14155776 / 8);
    conv_bf16_kernel<<<2048, 256, 0, stream>>>(fc2w, fc2w_b, 14155776 / 8);
    conv_bf16_kernel<<<2048, 256, 0, stream>>>(decw, decw_b, 24576000 / 8);

    for (int l = 0; l < 6; ++l) {
      ln_kernel<<<4096, 256, 0, stream>>>(x, ln1g + l * 768, ln1b + l * 768, h);
      gemm_bb<0, 0><<<dim3(18, 32), 256, 0, stream>>>(
          h, attnw_b + (size_t)l * 2304 * 768, attnb + l * 2304, qkv, nullptr,
          nullptr, nullptr, 2304, 768);
      vtrans_kernel<<<dim3(32, 12, 2), 256, 0, stream>>>(qkv, vt);
      attn_kernel<<<dim3(32, 12, 2), 256, 0, stream>>>(qkv, vt, y);
      gemm_bb<2, 0><<<dim3(6, 32), 256, 0, stream>>>(
          y, projw_b + (size_t)l * 768 * 768, projb + l * 768, nullptr, nullptr,
          x, nullptr, 768, 768);
      ln_kernel<<<4096, 256, 0, stream>>>(x, ln2g + l * 768, ln2b + l * 768, h);
      gemm_bb<1, 0><<<dim3(24, 32), 256, 0, stream>>>(
          h, fc1w_b + (size_t)l * 3072 * 768, fc1b + l * 3072, h2, nullptr,
          nullptr, nullptr, 3072, 768);
      gemm_bb<2, 0><<<dim3(6, 32), 256, 0, stream>>>(
          h2, fc2w_b + (size_t)l * 768 * 3072, fc2b + l * 768, nullptr, nullptr,
          x, (l == 5) ? h : nullptr, 768, 3072);
    }
    gemm_bb<3, 1><<<dim3(32, 250), 256, 0, stream>>>(
        h, decw_b, nullptr, nullptr, (float*)d_out, nullptr, nullptr, 32000,
        768);
  } else {
    for (int l = 0; l < 6; ++l) {
      ln_kernel<<<4096, 256, 0, stream>>>(x, ln1g + l * 768, ln1b + l * 768, h);
      gemm_bt<0><<<dim3(18, 32), 256, 0, stream>>>(
          h, attnw + (size_t)l * 2304 * 768, attnb + l * 2304, qkv, nullptr,
          nullptr, nullptr, 2304, 768);
      vtrans_kernel<<<dim3(32, 12, 2), 256, 0, stream>>>(qkv, vt);
      attn_kernel<<<dim3(32, 12, 2), 256, 0, stream>>>(qkv, vt, y);
      gemm_bt<2><<<dim3(6, 32), 256, 0, stream>>>(
          y, projw + (size_t)l * 768 * 768, projb + l * 768, nullptr, nullptr,
          x, nullptr, 768, 768);
      ln_kernel<<<4096, 256, 0, stream>>>(x, ln2g + l * 768, ln2b + l * 768, h);
      gemm_bt<1><<<dim3(24, 32), 256, 0, stream>>>(
          h, fc1w + (size_t)l * 3072 * 768, fc1b + l * 3072, h2, nullptr,
          nullptr, nullptr, 3072, 768);
      gemm_bt<2><<<dim3(6, 32), 256, 0, stream>>>(
          h2, fc2w + (size_t)l * 768 * 3072, fc2b + l * 768, nullptr, nullptr,
          x, (l == 5) ? h : nullptr, 768, 3072);
    }
    gemm_bt<3><<<dim3(250, 32), 256, 0, stream>>>(
        h, decw, nullptr, nullptr, (float*)d_out, nullptr, nullptr, 32000, 768);
  }
}